// Round 4
// baseline (237.639 us; speedup 1.0000x reference)
//
#include <hip/hip_runtime.h>

// TELIF: temporal-encoding LIF neuron scan.
// tx: [T, B, N] fp32, TE: [N, T] fp32, out ty: [T, B, N] fp32 (0/1 spikes).
// T=512, B=64, N=1024. One thread per (b,n) sequence; sequential over t.
//
// v5: depth-2 continuous load pipeline (4 rotating register buffers).
//   Evidence so far: occupancy is problem-capped at 4 waves/CU (1/SIMD), so
//   only per-wave ILP hides latency. v1/v4 (depth-1 prefetch) drain ALL
//   outstanding loads at every chunk boundary -> bursty issue, ~17KB/CU
//   avg in flight, 2.55 TB/s realized. v3 (LDS producer/consumer) showed
//   barrier machinery costs more than it saves. Here: at chunk k, issue
//   chunk k+2's loads and compute chunk k. The wait for chunk k+1 is then
//   for loads issued TWO chunk-periods ago; vmcnt decrements in order and
//   the compiler emits precise per-use counted waits, so the 63-slot vmem
//   queue stays continuously full (~40 loads + stores outstanding/wave).
//   All buffer indices compile-time (unroll-4 inner body) -> pure registers.
//   No swizzle (tx/out are single-use streams, zero inter-block reuse).
//   FETCH_SIZE ~74MB is set by harness poison-fill eviction of L3, not by
//   our cache hints (v4 falsified the nt-load theory) -> plain loads.

#define T_STEPS 512
#define BATCH   64
#define NNEUR   1024
#define BN      (BATCH * NNEUR)
#define UCHUNK  16
#define NCHUNK  (T_STEPS / UCHUNK)   // 32

__global__ __launch_bounds__(256) void telif_kernel(
    const float* __restrict__ tx, const float* __restrict__ TE,
    float* __restrict__ out)
{
    // Reference is validated against fp32 elementwise ops with a hard
    // (v > th) threshold: forbid FMA contraction so rounding matches exactly.
#pragma clang fp contract(off)

    const int flat = blockIdx.x * 256 + threadIdx.x;   // b*N + n
    const int n = flat & (NNEUR - 1);

    const float* tep = TE + n * T_STEPS;  // contiguous along t per thread
    float*       outp = out + flat;

    float v  = 0.0f;   // REST
    float y  = 0.0f;
    float th = 0.3f;   // THRESHOLD

    // 4 rotating chunk buffers; chunk k lives in buffer k&3. Depth-2:
    // while computing k, chunks k+1 and k+2 are in flight.
    float xb[4][UCHUNK], tb[4][UCHUNK];

    // Prologue: issue chunks 0 and 1 (no waits emitted until first use).
#pragma unroll
    for (int c = 0; c < 2; ++c) {
#pragma unroll
        for (int u = 0; u < UCHUNK; ++u)
            xb[c][u] = tx[(size_t)(c * UCHUNK + u) * BN + flat];
#pragma unroll
        for (int u = 0; u < UCHUNK; u += 4) {
            float4 f = *reinterpret_cast<const float4*>(tep + c * UCHUNK + u);
            tb[c][u] = f.x; tb[c][u+1] = f.y; tb[c][u+2] = f.z; tb[c][u+3] = f.w;
        }
    }

#pragma unroll 1
    for (int s = 0; s < NCHUNK / 4; ++s) {     // 8 super-iterations x 4 chunks
#pragma unroll
        for (int c = 0; c < 4; ++c) {
            const int k = s * 4 + c;           // chunk index
            const int t = k * UCHUNK;

            // Issue chunk k+2 into buffer (c+2)&3 (compile-time index).
            // Uniform branch (s is wave-uniform): only the last two chunks
            // skip. Issue BEFORE this chunk's stores so the eventual waits
            // for these loads never imply a store drain.
            if (k + 2 < NCHUNK) {
                const int t2 = t + 2 * UCHUNK;
#pragma unroll
                for (int u = 0; u < UCHUNK; ++u)
                    xb[(c + 2) & 3][u] = tx[(size_t)(t2 + u) * BN + flat];
#pragma unroll
                for (int u = 0; u < UCHUNK; u += 4) {
                    float4 f = *reinterpret_cast<const float4*>(tep + t2 + u);
                    tb[(c + 2) & 3][u]     = f.x;
                    tb[(c + 2) & 3][u + 1] = f.y;
                    tb[(c + 2) & 3][u + 2] = f.z;
                    tb[(c + 2) & 3][u + 3] = f.w;
                }
            }

            // Compute chunk k. Exact op order of the reference:
            //   th = th + v*te - (th - THRESHOLD)*BETA
            //   v  = v*DECAY*(1-y) + x
            //   y  = (v > th)
#pragma unroll
            for (int u = 0; u < UCHUNK; ++u) {
                float a    = v * tb[c][u];
                float bsum = th + a;
                float cc   = th - 0.3f;
                float d    = cc * 0.02f;
                th = bsum - d;
                float e  = v * 0.2f;
                float f1 = 1.0f - y;
                float g  = e * f1;
                v = g + xb[c][u];
                y = (v > th) ? 1.0f : 0.0f;
                __builtin_nontemporal_store(y, outp + (size_t)(t + u) * BN);
            }
        }
    }
}

extern "C" void kernel_launch(void* const* d_in, const int* in_sizes, int n_in,
                              void* d_out, int out_size, void* d_ws, size_t ws_size,
                              hipStream_t stream) {
    const float* tx = (const float*)d_in[0];  // [T, B, N]
    const float* TE = (const float*)d_in[1];  // [N, T]
    float* out = (float*)d_out;               // [T, B, N]
    telif_kernel<<<BN / 256, 256, 0, stream>>>(tx, TE, out);
}